// Round 6
// baseline (62.529 us; speedup 1.0000x reference)
//
#include <hip/hip_runtime.h>
#include <hip/hip_bf16.h>
#include <math.h>

#define HW 56
#define PPI (HW*HW)          // 3136 pixels per image
#define NB 4
#define C 128
#define NPIX (NB*PPI)        // 12544

typedef __attribute__((ext_vector_type(8))) short short8;
typedef __attribute__((ext_vector_type(4))) float f32x4;

__device__ __forceinline__ short bfbits(float v) {
    __hip_bfloat16 hb = __float2bfloat16(v);
    return *reinterpret_cast<short*>(&hb);
}
__device__ __forceinline__ unsigned packbf(float a, float b) {
    return (unsigned)(unsigned short)bfbits(a) | ((unsigned)(unsigned short)bfbits(b) << 16);
}

// ---------- Kernel 1: weight prep (qkv B-frags + conv B-frags) — r5 verbatim -----------
__global__ __launch_bounds__(256) void prep_kernel(
    const float* __restrict__ cw,
    const float* __restrict__ qw, const float* __restrict__ kw,
    const float* __restrict__ vw,
    __hip_bfloat16* __restrict__ wcf, __hip_bfloat16* __restrict__ wqkv)
{
    int gid = blockIdx.x * 256 + threadIdx.x;
    if (blockIdx.x < 192) {
        int m   = gid >> 14;
        int r   = gid & 16383;
        int col = r >> 7;
        int k   = r & 127;
        const float* W = (m == 0) ? qw : (m == 1) ? kw : vw;
        int kk = k >> 5, hi = (k >> 3) & 3, j = k & 7;
        wqkv[m * 16384 + ((kk * 4 + hi) * 128 + col) * 8 + j] = __float2bfloat16(W[col * 128 + k]);
    } else {
        int idx = gid - 192 * 256;          // 0..4095
        int hi = idx >> 10, cout = (idx >> 3) & 127, j = idx & 7;
        int k  = hi * 8 + j;
        float v = (k < 27) ? cw[cout * 27 + k] : 0.f;
        wcf[(hi * 128 + cout) * 8 + j] = __float2bfloat16(v);
    }
}

// ---------- Kernel 2: fully fused conv3x3s2+relu -> qkv -> 7x7 NAT ---------------------
// One block per 4x4 output tile (784 blocks). All intermediates in LDS.
#define VPITCH 272   // bytes per vT / attnW row (136 shorts)

__global__ __launch_bounds__(256, 2) void fused_kernel(
    const float* __restrict__ x, const __hip_bfloat16* __restrict__ wcf,
    const float* __restrict__ cb, const __hip_bfloat16* __restrict__ wqkv,
    const float* __restrict__ qb, const float* __restrict__ kb,
    const float* __restrict__ vb, float* __restrict__ out)
{
    __shared__ __align__(16) short k_lds[112 * 128];   // 28672 B, 256B rows, unit ^ (n&15)
    __shared__ __align__(16) short vT[128 * 136];      // 34816 B, r5 layout (XOR bits 4-6)
    __shared__ __align__(16) short q_lds[16 * 128];    //  4096 B, f_lds-style swizzle
    __shared__ __align__(16) char  uni_s[16 * 116 * 4];//  7424 B: f_ch (4KB) / logit_s union
    __shared__ __align__(16) short attnW[16 * 136];    //  4352 B
    short* f_ch    = (short*)uni_s;
    float* logit_s = (float*)uni_s;

    int t = threadIdx.x, lane = t & 63, wid = t >> 6;
    int r16 = lane & 15, hi = lane >> 4;

    int bx = blockIdx.x;                 // 4 * 196
    int b  = bx / 196;
    int rr = bx % 196;
    int th = rr / 14, tw = rr % 14;
    int ih0 = min(max(th*4 - 3, 0), HW - 10);
    int iw0 = min(max(tw*4 - 3, 0), HW - 10);

    // zero attnW; zero vT LOGICAL units 14,15 (n in [112,128) — never written, read by PV)
    {
        unsigned* aw = (unsigned*)attnW;
        for (int i = t; i < 1088; i += 256) aw[i] = 0u;
        for (int i = t; i < 1024; i += 256) {
            int c = i >> 3, j = i & 7;
            int hsw = (c >> 3) & 7;
            int unit = (14 + (j >> 2)) ^ hsw;
            *(unsigned*)((char*)vT + c*VPITCH + (unit << 4) + (j & 3)*4) = 0u;
        }
    }

    // hoisted conv B-fragments for this wave's two col-tiles
    int cout0 = (wid*2 + 0)*16 + r16;
    int cout1 = (wid*2 + 1)*16 + r16;
    short8 cbw0 = *(const short8*)((const short*)wcf + (hi*128 + cout0)*8);
    short8 cbw1 = *(const short8*)((const short*)wcf + (hi*128 + cout1)*8);

    // conv for one 16-pixel chunk (lane row r16 -> pixel (hf,wf)) into f_ch
    auto conv_to_fch = [&](int hf, int wf) {
        short8 af;
        #pragma unroll
        for (int j = 0; j < 8; ++j) {
            int k = hi*8 + j;
            float xv = 0.f;
            if (k < 27) {
                int ci = k/9, r9 = k%9, kh = r9/3, kw_ = r9%3;
                int ih = 2*hf - 1 + kh, iw = 2*wf - 1 + kw_;
                if (ih >= 0 && ih < 112 && iw >= 0 && iw < 112)
                    xv = x[((size_t)(b*3 + ci)*112 + ih)*112 + iw];
            }
            af[j] = bfbits(xv);
        }
        #pragma unroll
        for (int ctl = 0; ctl < 2; ++ctl) {
            int cout  = ctl ? cout1 : cout0;
            short8 bw = ctl ? cbw1  : cbw0;
            f32x4 acc = {0.f, 0.f, 0.f, 0.f};
            acc = __builtin_amdgcn_mfma_f32_16x16x32_bf16(af, bw, acc, 0, 0, 0);
            float bias = cb[cout];
            int colblk = cout >> 3, inb = (cout & 7)*2;
            #pragma unroll
            for (int rg = 0; rg < 4; ++rg) {
                int px = hi*4 + rg;
                *(short*)((char*)f_ch + px*256 + ((colblk ^ px) << 4) + inb)
                    = bfbits(fmaxf(acc[rg] + bias, 0.f));
            }
        }
    };

    // ---- chunks 0..6: k & v for 112 halo pixels (n >= 100 clamped -> dup rows) ----
    for (int cc = 0; cc < 7; ++cc) {
        int nc = min(cc*16 + r16, 99);
        conv_to_fch(ih0 + nc/10, iw0 + nc%10);
        __syncthreads();

        short8 fa[4];
        #pragma unroll
        for (int kk = 0; kk < 4; ++kk)
            fa[kk] = *(const short8*)((char*)f_ch + r16*256 + (((kk*4 + hi) ^ r16) << 4));

        #pragma unroll
        for (int i = 0; i < 4; ++i) {
            int idx = wid*4 + i;       // 0..15, wave-uniform
            int mv  = idx >> 3;        // 0 = k, 1 = v
            int ct  = idx & 7;
            const short* wb = (const short*)wqkv + (1+mv)*16384 + hi*1024 + r16*8 + ct*128;
            f32x4 acc = {0.f, 0.f, 0.f, 0.f};
            acc = __builtin_amdgcn_mfma_f32_16x16x32_bf16(fa[0], *(const short8*)(wb),         acc, 0, 0, 0);
            acc = __builtin_amdgcn_mfma_f32_16x16x32_bf16(fa[1], *(const short8*)(wb +  4096), acc, 0, 0, 0);
            acc = __builtin_amdgcn_mfma_f32_16x16x32_bf16(fa[2], *(const short8*)(wb +  8192), acc, 0, 0, 0);
            acc = __builtin_amdgcn_mfma_f32_16x16x32_bf16(fa[3], *(const short8*)(wb + 12288), acc, 0, 0, 0);
            int c = ct*16 + r16;
            if (mv == 0) {
                float bb = kb[c];
                int swz = c >> 3;
                #pragma unroll
                for (int rg = 0; rg < 4; ++rg) {
                    int n = cc*16 + hi*4 + rg;
                    *(short*)((char*)k_lds + n*256 + ((swz ^ (n & 15)) << 4) + (c & 7)*2)
                        = bfbits(acc[rg] + bb);
                }
            } else {
                float bb = vb[c];
                int n0 = cc*16 + hi*4;
                unsigned lo  = packbf(acc[0] + bb, acc[1] + bb);
                unsigned hi2 = packbf(acc[2] + bb, acc[3] + bb);
                int hsw = (c >> 3) & 7;
                int off = (2*n0) ^ (hsw << 4);      // 2*n0 = 32cc+8hi, 8B-aligned, XOR-safe
                *(uint2*)((char*)vT + c*VPITCH + off) = make_uint2(lo, hi2);
            }
        }
        __syncthreads();
    }

    // ---- chunk 7: q for the 16 center pixels ----
    {
        int ph = th*4 + (r16 >> 2), pw = tw*4 + (r16 & 3);
        conv_to_fch(ph, pw);
        __syncthreads();

        short8 fa[4];
        #pragma unroll
        for (int kk = 0; kk < 4; ++kk)
            fa[kk] = *(const short8*)((char*)f_ch + r16*256 + (((kk*4 + hi) ^ r16) << 4));

        #pragma unroll
        for (int i = 0; i < 2; ++i) {
            int ct = wid*2 + i;
            const short* wb = (const short*)wqkv + hi*1024 + r16*8 + ct*128;
            f32x4 acc = {0.f, 0.f, 0.f, 0.f};
            acc = __builtin_amdgcn_mfma_f32_16x16x32_bf16(fa[0], *(const short8*)(wb),         acc, 0, 0, 0);
            acc = __builtin_amdgcn_mfma_f32_16x16x32_bf16(fa[1], *(const short8*)(wb +  4096), acc, 0, 0, 0);
            acc = __builtin_amdgcn_mfma_f32_16x16x32_bf16(fa[2], *(const short8*)(wb +  8192), acc, 0, 0, 0);
            acc = __builtin_amdgcn_mfma_f32_16x16x32_bf16(fa[3], *(const short8*)(wb + 12288), acc, 0, 0, 0);
            int c = ct*16 + r16;
            float bb = qb[c];
            #pragma unroll
            for (int rg = 0; rg < 4; ++rg) {
                int px = hi*4 + rg;
                *(short*)((char*)q_lds + px*256 + (((c >> 3) ^ px) << 4) + (c & 7)*2)
                    = bfbits(acc[rg] + bb);
            }
        }
        __syncthreads();
    }

    // ---- QK^T: logits[16][112] from q_lds / k_lds ----
    short8 qa[4];
    #pragma unroll
    for (int kk = 0; kk < 4; ++kk)
        qa[kk] = *(const short8*)((char*)q_lds + r16*256 + (((kk*4 + hi) ^ r16) << 4));

    for (int nt = wid; nt < 7; nt += 4) {
        const char* kb_ = (const char*)k_lds + (nt*16 + r16)*256;
        f32x4 acc = {0.f, 0.f, 0.f, 0.f};
        #pragma unroll
        for (int kk = 0; kk < 4; ++kk) {
            short8 kv = *(const short8*)(kb_ + (((kk*4 + hi) ^ r16) << 4));
            acc = __builtin_amdgcn_mfma_f32_16x16x32_bf16(qa[kk], kv, acc, 0, 0, 0);
        }
        #pragma unroll
        for (int rg = 0; rg < 4; ++rg)
            logit_s[(hi*4 + rg)*116 + nt*16 + r16] = acc[rg];
    }
    __syncthreads();

    // ---- softmax per pixel, scatter bf16 weights into attnW (r5 verbatim) ----
    {
        int r7 = lane / 7, s7 = lane - 7*r7;
        bool valid = lane < 49;
        const float scale = 0.08838834764831845f;   // 128^-0.5
        #pragma unroll
        for (int px = 0; px < 4; ++px) {
            int p = wid*4 + px;
            int h = th*4 + (p >> 2), w = tw*4 + (p & 3);
            int hs = min(max(h - 3, 0), HW - 7);
            int ws = min(max(w - 3, 0), HW - 7);
            int col = (hs - ih0 + r7)*10 + (ws - iw0 + s7);
            float lg = valid ? logit_s[p*116 + col] * scale : -INFINITY;
            float m = lg;
            #pragma unroll
            for (int d = 1; d < 64; d <<= 1) m = fmaxf(m, __shfl_xor(m, d));
            float e = valid ? __expf(lg - m) : 0.f;
            float s = e;
            #pragma unroll
            for (int d = 1; d < 64; d <<= 1) s += __shfl_xor(s, d);
            if (valid) {
                __hip_bfloat16 hb = __float2bfloat16(e / s);
                *(__hip_bfloat16*)((char*)attnW + p*VPITCH + 2*col) = hb;
            }
        }
    }
    __syncthreads();

    // ---- PV: out[16][128] = attnW x vT^T (r5 verbatim) ----
    short8 pa[4];
    #pragma unroll
    for (int kk = 0; kk < 4; ++kk)
        pa[kk] = *(const short8*)((char*)attnW + r16*VPITCH + kk*64 + hi*16);

    for (int nt = wid; nt < 8; nt += 4) {
        int c   = nt*16 + r16;
        int hsw = (c >> 3) & 7;
        const char* vrow = (const char*)vT + c*VPITCH;
        f32x4 acc = {0.f, 0.f, 0.f, 0.f};
        #pragma unroll
        for (int kk = 0; kk < 4; ++kk) {
            short8 vbr = *(const short8*)(vrow + ((kk*64 + hi*16) ^ (hsw << 4)));
            acc = __builtin_amdgcn_mfma_f32_16x16x32_bf16(pa[kk], vbr, acc, 0, 0, 0);
        }
        #pragma unroll
        for (int rg = 0; rg < 4; ++rg) {
            int p = hi*4 + rg;
            int h = th*4 + (p >> 2), w = tw*4 + (p & 3);
            out[(((size_t)b*C + c)*HW + h)*HW + w] = acc[rg];
        }
    }
}

extern "C" void kernel_launch(void* const* d_in, const int* in_sizes, int n_in,
                              void* d_out, int out_size, void* d_ws, size_t ws_size,
                              hipStream_t stream) {
    const float* x      = (const float*)d_in[0];
    const float* conv_w = (const float*)d_in[1];
    const float* conv_b = (const float*)d_in[2];
    const float* q_w    = (const float*)d_in[3];
    const float* q_b    = (const float*)d_in[4];
    const float* k_w    = (const float*)d_in[5];
    const float* k_b    = (const float*)d_in[6];
    const float* v_w    = (const float*)d_in[7];
    const float* v_b    = (const float*)d_in[8];
    float* out = (float*)d_out;

    __hip_bfloat16* wqkv = (__hip_bfloat16*)d_ws;        // 3*16384
    __hip_bfloat16* wcf  = wqkv + 3 * 16384;             // 4096

    prep_kernel<<<208, 256, 0, stream>>>(conv_w, q_w, k_w, v_w, wcf, wqkv);
    fused_kernel<<<NB*196, 256, 0, stream>>>(x, wcf, conv_b, wqkv,
                                             q_b, k_b, v_b, out);
}

// Round 7
// 42.931 us; speedup vs baseline: 1.4565x; 1.4565x over previous
//
#include <hip/hip_runtime.h>
#include <hip/hip_bf16.h>
#include <math.h>

#define HW 56
#define PPI (HW*HW)          // 3136 pixels per image
#define NB 4
#define C 128
#define NPIX (NB*PPI)        // 12544

typedef __attribute__((ext_vector_type(8))) short short8;
typedef __attribute__((ext_vector_type(4))) float f32x4;

__device__ __forceinline__ short bfbits(float v) {
    __hip_bfloat16 hb = __float2bfloat16(v);
    return *reinterpret_cast<short*>(&hb);
}
__device__ __forceinline__ unsigned packbf(float a, float b) {
    return (unsigned)(unsigned short)bfbits(a) | ((unsigned)(unsigned short)bfbits(b) << 16);
}

// ---------- Kernel 1: weight prep (qkv B-frags + conv B-frags) — unchanged -------------
__global__ __launch_bounds__(256) void prep_kernel(
    const float* __restrict__ cw,
    const float* __restrict__ qw, const float* __restrict__ kw,
    const float* __restrict__ vw,
    __hip_bfloat16* __restrict__ wcf, __hip_bfloat16* __restrict__ wqkv)
{
    int gid = blockIdx.x * 256 + threadIdx.x;
    if (blockIdx.x < 192) {
        int m   = gid >> 14;
        int r   = gid & 16383;
        int col = r >> 7;
        int k   = r & 127;
        const float* W = (m == 0) ? qw : (m == 1) ? kw : vw;
        int kk = k >> 5, hi = (k >> 3) & 3, j = k & 7;
        wqkv[m * 16384 + ((kk * 4 + hi) * 128 + col) * 8 + j] = __float2bfloat16(W[col * 128 + k]);
    } else {
        int idx = gid - 192 * 256;          // 0..4095
        int hi = idx >> 10, cout = (idx >> 3) & 127, j = idx & 7;
        int k  = hi * 8 + j;
        float v = (k < 27) ? cw[cout * 27 + k] : 0.f;
        wcf[(hi * 128 + cout) * 8 + j] = __float2bfloat16(v);
    }
}

// ---------- Kernel 2: fully fused conv3x3s2+relu -> qkv -> 7x7 NAT ---------------------
// One block per 4x4 output tile (784 blocks). x patch staged coalesced into LDS (bf16),
// conv im2col reads from LDS; biases hoisted; rest identical to r6.
#define VPITCH 272   // bytes per vT / attnW row (136 shorts)
#define XPITCH 24    // shorts per x_lds row
#define XCH    504   // 21*24 shorts per channel

__global__ __launch_bounds__(256, 2) void fused_kernel(
    const float* __restrict__ x, const __hip_bfloat16* __restrict__ wcf,
    const float* __restrict__ cb, const __hip_bfloat16* __restrict__ wqkv,
    const float* __restrict__ qb, const float* __restrict__ kb,
    const float* __restrict__ vb, float* __restrict__ out)
{
    __shared__ __align__(16) short k_lds[112 * 128];   // 28672 B, 256B rows, unit ^ (n&15)
    __shared__ __align__(16) short vT[128 * 136];      // 34816 B (XOR bits 4-6, pitch 272)
    __shared__ __align__(16) short q_lds[16 * 128];    //  4096 B
    __shared__ __align__(16) char  uni_s[16 * 116 * 4];//  7424 B: f_ch (4KB) / logit_s union
    __shared__ __align__(16) short attnW[16 * 136];    //  4352 B; first 3072B alias x_lds
    short* f_ch    = (short*)uni_s;
    float* logit_s = (float*)uni_s;
    short* x_lds   = attnW;            // alive: staging .. chunk-7 conv; attnW used after

    int t = threadIdx.x, lane = t & 63, wid = t >> 6;
    int r16 = lane & 15, hi = lane >> 4;

    int bx = blockIdx.x;                 // 4 * 196
    int b  = bx / 196;
    int rr = bx % 196;
    int th = rr / 14, tw = rr % 14;
    int ih0 = min(max(th*4 - 3, 0), HW - 10);
    int iw0 = min(max(tw*4 - 3, 0), HW - 10);

    // ---- stage x patch: 3ch x 21x21 f32 -> bf16 LDS, zero-filled at borders ----
    {
        int ihA = 2*ih0 - 1, iwA = 2*iw0 - 1;
        #pragma unroll
        for (int it = 0; it < 6; ++it) {
            int i = t + 256*it;            // 0..1535, 1512 used
            if (i < 1512) {
                int ci = i / XCH, r = i % XCH;
                int row = r / XPITCH, col = r % XPITCH;
                int ih = ihA + row, iw = iwA + col;
                float xv = 0.f;
                if (col < 21 && ih >= 0 && ih < 112 && iw >= 0 && iw < 112)
                    xv = x[((size_t)(b*3 + ci)*112 + ih)*112 + iw];
                x_lds[i] = bfbits(xv);
            }
        }
    }

    // zero vT LOGICAL units 14,15 (n in [112,128) — never written, read by PV)
    for (int i = t; i < 1024; i += 256) {
        int c = i >> 3, j = i & 7;
        int hsw = (c >> 3) & 7;
        int unit = (14 + (j >> 2)) ^ hsw;
        *(unsigned*)((char*)vT + c*VPITCH + (unit << 4) + (j & 3)*4) = 0u;
    }

    // ---- hoisted per-lane constants: im2col offsets, biases, conv B-frags ----
    int cout0 = (wid*2 + 0)*16 + r16;
    int cout1 = (wid*2 + 1)*16 + r16;
    short8 cbw0 = *(const short8*)((const short*)wcf + (hi*128 + cout0)*8);
    short8 cbw1 = *(const short8*)((const short*)wcf + (hi*128 + cout1)*8);
    float cbias0 = cb[cout0], cbias1 = cb[cout1];

    int  offb[8];
    bool vmask[8];
    #pragma unroll
    for (int j = 0; j < 8; ++j) {
        int k = hi*8 + j;
        int ci = k/9, r9 = k%9, kh = r9/3, kw_ = r9%3;
        offb[j]  = ci*XCH + kh*XPITCH + kw_;
        vmask[j] = (k < 27);
    }

    float kvbias[4];
    #pragma unroll
    for (int i = 0; i < 4; ++i) {
        int idx = wid*4 + i, mv = idx >> 3, ct = idx & 7, c = ct*16 + r16;
        kvbias[i] = mv ? vb[c] : kb[c];
    }
    float qbias[2];
    #pragma unroll
    for (int i = 0; i < 2; ++i) qbias[i] = qb[(wid*2 + i)*16 + r16];

    __syncthreads();   // x_lds ready

    // conv for one 16-pixel chunk (lane row r16 -> LOCAL window pixel (hl,wl)) into f_ch
    auto conv_to_fch = [&](int hl, int wl) {
        int pb = hl*(2*XPITCH) + wl*2;
        short8 af;
        #pragma unroll
        for (int j = 0; j < 8; ++j)
            af[j] = vmask[j] ? x_lds[offb[j] + pb] : (short)0;
        #pragma unroll
        for (int ctl = 0; ctl < 2; ++ctl) {
            int cout   = ctl ? cout1  : cout0;
            short8 bw  = ctl ? cbw1   : cbw0;
            float bias = ctl ? cbias1 : cbias0;
            f32x4 acc = {0.f, 0.f, 0.f, 0.f};
            acc = __builtin_amdgcn_mfma_f32_16x16x32_bf16(af, bw, acc, 0, 0, 0);
            int colblk = cout >> 3, inb = (cout & 7)*2;
            #pragma unroll
            for (int rg = 0; rg < 4; ++rg) {
                int px = hi*4 + rg;
                *(short*)((char*)f_ch + px*256 + ((colblk ^ px) << 4) + inb)
                    = bfbits(fmaxf(acc[rg] + bias, 0.f));
            }
        }
    };

    // ---- chunks 0..6: k & v for 112 halo pixels (n >= 100 clamped -> dup rows) ----
    for (int cc = 0; cc < 7; ++cc) {
        int nc = min(cc*16 + r16, 99);
        conv_to_fch(nc/10, nc%10);
        __syncthreads();

        short8 fa[4];
        #pragma unroll
        for (int kk = 0; kk < 4; ++kk)
            fa[kk] = *(const short8*)((char*)f_ch + r16*256 + (((kk*4 + hi) ^ r16) << 4));

        #pragma unroll
        for (int i = 0; i < 4; ++i) {
            int idx = wid*4 + i;       // 0..15, wave-uniform
            int mv  = idx >> 3;        // 0 = k, 1 = v
            int ct  = idx & 7;
            const short* wb = (const short*)wqkv + (1+mv)*16384 + hi*1024 + r16*8 + ct*128;
            f32x4 acc = {0.f, 0.f, 0.f, 0.f};
            acc = __builtin_amdgcn_mfma_f32_16x16x32_bf16(fa[0], *(const short8*)(wb),         acc, 0, 0, 0);
            acc = __builtin_amdgcn_mfma_f32_16x16x32_bf16(fa[1], *(const short8*)(wb +  4096), acc, 0, 0, 0);
            acc = __builtin_amdgcn_mfma_f32_16x16x32_bf16(fa[2], *(const short8*)(wb +  8192), acc, 0, 0, 0);
            acc = __builtin_amdgcn_mfma_f32_16x16x32_bf16(fa[3], *(const short8*)(wb + 12288), acc, 0, 0, 0);
            int c = ct*16 + r16;
            float bb = kvbias[i];
            if (mv == 0) {
                int swz = c >> 3;
                #pragma unroll
                for (int rg = 0; rg < 4; ++rg) {
                    int n = cc*16 + hi*4 + rg;
                    *(short*)((char*)k_lds + n*256 + ((swz ^ (n & 15)) << 4) + (c & 7)*2)
                        = bfbits(acc[rg] + bb);
                }
            } else {
                int n0 = cc*16 + hi*4;
                unsigned lo  = packbf(acc[0] + bb, acc[1] + bb);
                unsigned hi2 = packbf(acc[2] + bb, acc[3] + bb);
                int hsw = (c >> 3) & 7;
                int off = (2*n0) ^ (hsw << 4);
                *(uint2*)((char*)vT + c*VPITCH + off) = make_uint2(lo, hi2);
            }
        }
        __syncthreads();
    }

    // ---- chunk 7: q for the 16 center pixels ----
    {
        int ph = th*4 + (r16 >> 2), pw = tw*4 + (r16 & 3);
        conv_to_fch(ph - ih0, pw - iw0);
        __syncthreads();           // all x_lds reads complete block-wide after this

        // zero attnW (aliases x_lds — safe now); concurrent with q GEMM
        {
            unsigned* aw = (unsigned*)attnW;
            for (int i = t; i < 1088; i += 256) aw[i] = 0u;
        }

        short8 fa[4];
        #pragma unroll
        for (int kk = 0; kk < 4; ++kk)
            fa[kk] = *(const short8*)((char*)f_ch + r16*256 + (((kk*4 + hi) ^ r16) << 4));

        #pragma unroll
        for (int i = 0; i < 2; ++i) {
            int ct = wid*2 + i;
            const short* wb = (const short*)wqkv + hi*1024 + r16*8 + ct*128;
            f32x4 acc = {0.f, 0.f, 0.f, 0.f};
            acc = __builtin_amdgcn_mfma_f32_16x16x32_bf16(fa[0], *(const short8*)(wb),         acc, 0, 0, 0);
            acc = __builtin_amdgcn_mfma_f32_16x16x32_bf16(fa[1], *(const short8*)(wb +  4096), acc, 0, 0, 0);
            acc = __builtin_amdgcn_mfma_f32_16x16x32_bf16(fa[2], *(const short8*)(wb +  8192), acc, 0, 0, 0);
            acc = __builtin_amdgcn_mfma_f32_16x16x32_bf16(fa[3], *(const short8*)(wb + 12288), acc, 0, 0, 0);
            int c = ct*16 + r16;
            float bb = qbias[i];
            #pragma unroll
            for (int rg = 0; rg < 4; ++rg) {
                int px = hi*4 + rg;
                *(short*)((char*)q_lds + px*256 + (((c >> 3) ^ px) << 4) + (c & 7)*2)
                    = bfbits(acc[rg] + bb);
            }
        }
        __syncthreads();
    }

    // ---- QK^T: logits[16][112] from q_lds / k_lds ----
    short8 qa[4];
    #pragma unroll
    for (int kk = 0; kk < 4; ++kk)
        qa[kk] = *(const short8*)((char*)q_lds + r16*256 + (((kk*4 + hi) ^ r16) << 4));

    for (int nt = wid; nt < 7; nt += 4) {
        const char* kb_ = (const char*)k_lds + (nt*16 + r16)*256;
        f32x4 acc = {0.f, 0.f, 0.f, 0.f};
        #pragma unroll
        for (int kk = 0; kk < 4; ++kk) {
            short8 kv = *(const short8*)(kb_ + (((kk*4 + hi) ^ r16) << 4));
            acc = __builtin_amdgcn_mfma_f32_16x16x32_bf16(qa[kk], kv, acc, 0, 0, 0);
        }
        #pragma unroll
        for (int rg = 0; rg < 4; ++rg)
            logit_s[(hi*4 + rg)*116 + nt*16 + r16] = acc[rg];
    }
    __syncthreads();

    // ---- softmax per pixel, scatter bf16 weights into attnW ----
    {
        int r7 = lane / 7, s7 = lane - 7*r7;
        bool valid = lane < 49;
        const float scale = 0.08838834764831845f;   // 128^-0.5
        #pragma unroll
        for (int px = 0; px < 4; ++px) {
            int p = wid*4 + px;
            int h = th*4 + (p >> 2), w = tw*4 + (p & 3);
            int hs = min(max(h - 3, 0), HW - 7);
            int ws = min(max(w - 3, 0), HW - 7);
            int col = (hs - ih0 + r7)*10 + (ws - iw0 + s7);
            float lg = valid ? logit_s[p*116 + col] * scale : -INFINITY;
            float m = lg;
            #pragma unroll
            for (int d = 1; d < 64; d <<= 1) m = fmaxf(m, __shfl_xor(m, d));
            float e = valid ? __expf(lg - m) : 0.f;
            float s = e;
            #pragma unroll
            for (int d = 1; d < 64; d <<= 1) s += __shfl_xor(s, d);
            if (valid) {
                __hip_bfloat16 hb = __float2bfloat16(e / s);
                *(__hip_bfloat16*)((char*)attnW + p*VPITCH + 2*col) = hb;
            }
        }
    }
    __syncthreads();

    // ---- PV: out[16][128] = attnW x vT^T ----
    short8 pa[4];
    #pragma unroll
    for (int kk = 0; kk < 4; ++kk)
        pa[kk] = *(const short8*)((char*)attnW + r16*VPITCH + kk*64 + hi*16);

    for (int nt = wid; nt < 8; nt += 4) {
        int c   = nt*16 + r16;
        int hsw = (c >> 3) & 7;
        const char* vrow = (const char*)vT + c*VPITCH;
        f32x4 acc = {0.f, 0.f, 0.f, 0.f};
        #pragma unroll
        for (int kk = 0; kk < 4; ++kk) {
            short8 vbr = *(const short8*)(vrow + ((kk*64 + hi*16) ^ (hsw << 4)));
            acc = __builtin_amdgcn_mfma_f32_16x16x32_bf16(pa[kk], vbr, acc, 0, 0, 0);
        }
        #pragma unroll
        for (int rg = 0; rg < 4; ++rg) {
            int p = hi*4 + rg;
            int h = th*4 + (p >> 2), w = tw*4 + (p & 3);
            out[(((size_t)b*C + c)*HW + h)*HW + w] = acc[rg];
        }
    }
}

extern "C" void kernel_launch(void* const* d_in, const int* in_sizes, int n_in,
                              void* d_out, int out_size, void* d_ws, size_t ws_size,
                              hipStream_t stream) {
    const float* x      = (const float*)d_in[0];
    const float* conv_w = (const float*)d_in[1];
    const float* conv_b = (const float*)d_in[2];
    const float* q_w    = (const float*)d_in[3];
    const float* q_b    = (const float*)d_in[4];
    const float* k_w    = (const float*)d_in[5];
    const float* k_b    = (const float*)d_in[6];
    const float* v_w    = (const float*)d_in[7];
    const float* v_b    = (const float*)d_in[8];
    float* out = (float*)d_out;

    __hip_bfloat16* wqkv = (__hip_bfloat16*)d_ws;        // 3*16384
    __hip_bfloat16* wcf  = wqkv + 3 * 16384;             // 4096

    prep_kernel<<<208, 256, 0, stream>>>(conv_w, q_w, k_w, v_w, wcf, wqkv);
    fused_kernel<<<NB*196, 256, 0, stream>>>(x, wcf, conv_b, wqkv,
                                             q_b, k_b, v_b, out);
}